// Round 4
// baseline (105.923 us; speedup 1.0000x reference)
//
#include <hip/hip_runtime.h>
#include <hip/hip_cooperative_groups.h>

namespace cg = cooperative_groups;

#define RES 128
#define NB 16
#define NPTS (RES * RES)

// ws layout (float2 units):
//   T : [NB][RES][RES]  (2 MB) intermediate after column (j->w) pass

__device__ __forceinline__ void cmac(float2& a, float2 u, float2 v) {
    a.x = fmaf(u.x, v.x, fmaf(-u.y, v.y, a.x));
    a.y = fmaf(u.x, v.y, fmaf( u.y, v.x, a.y));
}

// Single cooperative kernel: grid 256 = (b, tile), block 512.
// Phase 1 (column pass): T[b,i,w] = sum_j s[b,i,j] * exp(i*2pi/W * b_j * (w-64))
//   where s = bilinear sample of k-space at trajectory row i, b_j = traj[2j+1].
// grid-wide sync (cross-XCD handoff of T).
// Phase 2 (row pass):  out[b,h,w] = sum_i exp(i*2pi/H * a_i * (h-64)) * T[b,i,w]
__global__ __launch_bounds__(512) void fused_nufft(
    const float* __restrict__ kin, const float* __restrict__ traj,
    float2* __restrict__ T, float* __restrict__ out)
{
    __shared__ float2 sS[8][RES];      // 8 KB  : sampled rows (ph1) / Fxt tile (ph2)
    __shared__ float2 FyT[32][RES];    // 32 KB : Fy tile (32 j-rows)
    const float TWO_PI = 6.283185307179586f;
    const int b  = blockIdx.x >> 4;
    const int t8 = (blockIdx.x & 15) * 8;     // i0 in phase 1, h0 in phase 2
    const int tid = threadIdx.x;
    const int w = tid & (RES - 1);
    const int g = tid >> 7;                   // 0..3 -> rows t8+2g, t8+2g+1

    // ================= phase 1: bilinear sample + column DFT =================
    const float2* img = (const float2*)kin;   // [B][H][W] complex
    #pragma unroll
    for (int k = 0; k < 2; ++k) {
        int idx = tid + k * 512;              // [0,1024)
        int ii = idx >> 7;
        int j  = idx & (RES - 1);
        int m  = (t8 + ii) * RES + j;
        float pr = traj[2 * m + 0] + 0.5f * RES;
        float pc = traj[2 * m + 1] + 0.5f * RES;
        float r0f = floorf(pr), c0f = floorf(pc);
        float wr = pr - r0f, wc = pc - c0f;
        int r0 = min(max((int)r0f, 0), RES - 1);
        int r1 = min(r0 + 1, RES - 1);
        int c0 = min(max((int)c0f, 0), RES - 1);
        int c1 = min(c0 + 1, RES - 1);
        const float2* pb = img + b * NPTS;
        float2 g00 = pb[r0 * RES + c0], g01 = pb[r0 * RES + c1];
        float2 g10 = pb[r1 * RES + c0], g11 = pb[r1 * RES + c1];
        float w00 = (1.f - wr) * (1.f - wc), w01 = (1.f - wr) * wc;
        float w10 = wr * (1.f - wc),         w11 = wr * wc;
        sS[ii][j] = make_float2(
            w00 * g00.x + w01 * g01.x + w10 * g10.x + w11 * g11.x,
            w00 * g00.y + w01 * g01.y + w10 * g10.y + w11 * g11.y);
    }
    __syncthreads();

    float2 a0 = make_float2(0.f, 0.f), a1 = make_float2(0.f, 0.f);
    const int jl = tid >> 4;                  // 0..31 (twiddle-tile row)
    const int w0 = (tid & 15) * 8;            // w-octet start

    for (int jt = 0; jt < 4; ++jt) {
        // Fy tile for j in [32*jt, 32*jt+32): 2 sincosf + 8-step recurrence
        float bj = traj[2 * (32 * jt + jl) + 1];
        float th = (TWO_PI / RES) * bj;
        float sn0, cs0, snr, csr;
        sincosf(th * (float)(w0 - RES / 2), &sn0, &cs0);
        sincosf(th, &snr, &csr);
        float zx = cs0, zy = sn0;
        #pragma unroll
        for (int k = 0; k < 8; ++k) {
            FyT[jl][w0 + k] = make_float2(zx, zy);
            float nx = fmaf(zx, csr, -zy * snr);
            zy = fmaf(zx, snr, zy * csr);
            zx = nx;
        }
        __syncthreads();

        #pragma unroll 8
        for (int jj = 0; jj < 32; ++jj) {
            float2 fy = FyT[jj][w];
            float2 s0 = sS[2 * g + 0][32 * jt + jj];
            float2 s1 = sS[2 * g + 1][32 * jt + jj];
            cmac(a0, s0, fy);
            cmac(a1, s1, fy);
        }
        __syncthreads();
    }

    T[(b * RES + t8 + 2 * g + 0) * RES + w] = a0;
    T[(b * RES + t8 + 2 * g + 1) * RES + w] = a1;

    // ============== grid-wide handoff (device-scope visibility) ==============
    __threadfence();
    cg::this_grid().sync();

    // ================= phase 2: row DFT =================
    #pragma unroll
    for (int k = 0; k < 2; ++k) {
        int idx = tid + k * 512;              // [0,1024)
        int hh = idx >> 7;
        int i  = idx & (RES - 1);
        float ai = traj[2 * (i * RES) + 0];
        float ang = (TWO_PI / RES) * ai * (float)(t8 + hh - RES / 2);
        float sn, cs;
        sincosf(ang, &sn, &cs);
        sS[hh][i] = make_float2(cs, sn);      // reuse sS as Fxt tile
    }
    __syncthreads();

    float2 b0 = make_float2(0.f, 0.f), b1 = make_float2(0.f, 0.f);
    #pragma unroll 4
    for (int i = 0; i < RES; ++i) {
        float2 tv = T[(b * RES + i) * RES + w];
        float2 f0 = sS[2 * g + 0][i];
        float2 f1 = sS[2 * g + 1][i];
        cmac(b0, f0, tv);
        cmac(b1, f1, tv);
    }

    int h = t8 + 2 * g;
    out[((b * 2 + 0) * RES + h) * RES + w] = b0.x;
    out[((b * 2 + 1) * RES + h) * RES + w] = b0.y;
    out[((b * 2 + 0) * RES + h + 1) * RES + w] = b1.x;
    out[((b * 2 + 1) * RES + h + 1) * RES + w] = b1.y;
}

extern "C" void kernel_launch(void* const* d_in, const int* in_sizes, int n_in,
                              void* d_out, int out_size, void* d_ws, size_t ws_size,
                              hipStream_t stream) {
    const float* kin  = (const float*)d_in[0];   // [16,1,128,128,2] f32
    const float* traj = (const float*)d_in[1];   // [16384,2] f32
    float* out = (float*)d_out;                  // [16,1,2,128,128] f32
    float2* T = (float2*)d_ws;                   // NB*NPTS float2

    void* args[] = {(void*)&kin, (void*)&traj, (void*)&T, (void*)&out};
    hipLaunchCooperativeKernel((void*)fused_nufft, dim3(NB * (RES / 8)), dim3(512),
                               args, 0, stream);
}

// Round 5
// 32.287 us; speedup vs baseline: 3.2807x; 3.2807x over previous
//
#include <hip/hip_runtime.h>

#define RES 128
#define NB 16
#define NPTS (RES * RES)
#define WS 8          // w-strip per block
#define SPAD 129      // sT row pad (float2): odd -> 2-way banks on both axes
#define FPAD 129      // FxtT row pad (aliases sT region)
#define TPAD 10       // Tt row pad (even: b128-aligned rows)

__device__ __forceinline__ void cmac(float2& a, float2 u, float2 v) {
    a.x = fmaf(u.x, v.x, fmaf(-u.y, v.y, a.x));
    a.y = fmaf(u.x, v.y, fmaf( u.y, v.x, a.y));
}

// One block = (batch b, 8-wide w-strip). Both DFT passes block-local; no grid sync.
// Phase 0: sample all 128x128 trajectory points -> sT[j][i]  (transposed store)
// Phase 1: Tt[i][wl] = sum_j sT[j][i] * Fy[j][wl]            (T strip in LDS)
// Phase 2: out[h][w] = sum_i Fxt[h,i] * Tt[i][wl]            (Fxt tiles alias sT)
__global__ __launch_bounds__(512) void fused_strip(
    const float* __restrict__ kin, const float* __restrict__ traj,
    float* __restrict__ out)
{
    __shared__ __align__(16) float2 sT[RES][SPAD];   // 132096 B (phase2: FxtT alias)
    __shared__ __align__(16) float2 Tt[RES][TPAD];   // 10240 B
    __shared__ __align__(16) float2 Fy[RES][WS];     // 8192 B   -> 147 KiB total

    const float TWO_PI = 6.283185307179586f;
    const int b   = blockIdx.x >> 4;
    const int ws0 = (blockIdx.x & 15) * WS;
    const int tid = threadIdx.x;

    const float2* img = (const float2*)kin + b * NPTS;   // [H][W] complex
    const float2* tp  = (const float2*)traj;             // [M] (row, col)

    // ---------- phase 0a: bilinear-sample all RES*RES points into sT[j][i]
    #pragma unroll 4
    for (int k = 0; k < NPTS / 512; ++k) {
        int m = tid + k * 512;
        int i = m >> 7, j = m & (RES - 1);
        float2 t2 = tp[m];
        float pr = t2.x + 64.f;
        float pc = t2.y + 64.f;
        float r0f = floorf(pr), c0f = floorf(pc);
        float wr = pr - r0f, wc = pc - c0f;
        int r0 = min(max((int)r0f, 0), RES - 1);
        int r1 = min(r0 + 1, RES - 1);
        int c0 = min(max((int)c0f, 0), RES - 1);
        int c1 = min(c0 + 1, RES - 1);
        float2 g00 = img[r0 * RES + c0], g01 = img[r0 * RES + c1];
        float2 g10 = img[r1 * RES + c0], g11 = img[r1 * RES + c1];
        float w00 = (1.f - wr) * (1.f - wc), w01 = (1.f - wr) * wc;
        float w10 = wr * (1.f - wc),         w11 = wr * wc;
        sT[j][i] = make_float2(
            w00 * g00.x + w01 * g01.x + w10 * g10.x + w11 * g11.x,
            w00 * g00.y + w01 * g01.y + w10 * g10.y + w11 * g11.y);
    }

    // ---------- phase 0b: Fy[j][w] = exp(i*(2pi/128)*b_j*(ws0+w-64)), 2/thread
    {
        int e = tid * 2;                 // entries e, e+1 share j (WS=8, e even)
        int j = e >> 3;
        int w = e & 7;
        float bj = tp[j].y;
        float th = (TWO_PI / RES) * bj;
        float s0, c0s, s1, c1s;
        sincosf(th * (float)(ws0 + w     - 64), &s0, &c0s);
        sincosf(th * (float)(ws0 + w + 1 - 64), &s1, &c1s);
        Fy[j][w]     = make_float2(c0s, s0);
        Fy[j][w + 1] = make_float2(c1s, s1);
    }
    __syncthreads();

    // ---------- phase 1: column DFT. thread = (i = tid&127, w-pair wp = tid>>7)
    {
        const int i  = tid & (RES - 1);
        const int wp = tid >> 7;                       // 0..3
        float2 a0 = make_float2(0.f, 0.f), a1 = make_float2(0.f, 0.f);
        #pragma unroll 8
        for (int j = 0; j < RES; ++j) {
            float2 sv  = sT[j][i];                     // lane-consecutive b64
            float4 fy2 = *(const float4*)&Fy[j][2 * wp]; // broadcast b128
            cmac(a0, sv, make_float2(fy2.x, fy2.y));
            cmac(a1, sv, make_float2(fy2.z, fy2.w));
        }
        *(float4*)&Tt[i][2 * wp] = make_float4(a0.x, a0.y, a1.x, a1.y);
    }
    __syncthreads();

    // ---------- phase 2: row DFT with Fxt tiles aliasing sT storage
    float2 (*FxtT)[FPAD] = reinterpret_cast<float2(*)[FPAD]>(&sT[0][0]);
    const int h  = tid & (RES - 1);
    const int wp = tid >> 7;                           // 0..3
    const int jl = tid >> 4;                           // 0..31 tile row
    const int o0 = (tid & 15) * 8;                     // h-octet start
    float2 b0 = make_float2(0.f, 0.f), b1 = make_float2(0.f, 0.f);

    for (int it = 0; it < 4; ++it) {
        {   // FxtT[ii][hh] = exp(i*(2pi/128)*a_{it*32+ii}*(hh-64)): 2 sincosf + recurrence
            int irow = it * 32 + jl;
            float ai = tp[irow * RES].x;
            float th = (TWO_PI / RES) * ai;
            float sn0, cs0, snr, csr;
            sincosf(th * (float)(o0 - 64), &sn0, &cs0);
            sincosf(th, &snr, &csr);
            float zx = cs0, zy = sn0;
            #pragma unroll
            for (int k = 0; k < 8; ++k) {
                FxtT[jl][o0 + k] = make_float2(zx, zy);
                float nx = fmaf(zx, csr, -zy * snr);
                zy = fmaf(zx, snr, zy * csr);
                zx = nx;
            }
        }
        __syncthreads();
        #pragma unroll 8
        for (int ii = 0; ii < 32; ++ii) {
            float2 fx  = FxtT[ii][h];                    // lane-consecutive b64
            float4 tv2 = *(const float4*)&Tt[it * 32 + ii][2 * wp]; // broadcast b128
            cmac(b0, fx, make_float2(tv2.x, tv2.y));
            cmac(b1, fx, make_float2(tv2.z, tv2.w));
        }
        __syncthreads();
    }

    // ---------- store: [B][1][2][H][W]; pair (w, w+1) as one 8 B store per plane
    float* o = out + b * 2 * NPTS;
    int wg = ws0 + 2 * wp;
    *(float2*)&o[h * RES + wg]         = make_float2(b0.x, b1.x);
    *(float2*)&o[NPTS + h * RES + wg]  = make_float2(b0.y, b1.y);
}

extern "C" void kernel_launch(void* const* d_in, const int* in_sizes, int n_in,
                              void* d_out, int out_size, void* d_ws, size_t ws_size,
                              hipStream_t stream) {
    const float* kin  = (const float*)d_in[0];   // [16,1,128,128,2] f32
    const float* traj = (const float*)d_in[1];   // [16384,2] f32
    float* out = (float*)d_out;                  // [16,1,2,128,128] f32
    fused_strip<<<NB * (RES / WS), 512, 0, stream>>>(kin, traj, out);
}

// Round 6
// 26.073 us; speedup vs baseline: 4.0626x; 1.2383x over previous
//
#include <hip/hip_runtime.h>

#define RES 128
#define NB 16
#define NPTS (RES * RES)

__device__ __forceinline__ void cmac(float2& a, float2 u, float2 v) {
    a.x = fmaf(u.x, v.x, fmaf(-u.y, v.y, a.x));
    a.y = fmaf(u.x, v.y, fmaf( u.y, v.x, a.y));
}

// exp(i*2*pi*rev) via hardware v_sin/v_cos (operand in revolutions, fract-reduced)
__device__ __forceinline__ float2 cis_rev(float rev) {
    float r = __builtin_amdgcn_fractf(rev);
    return make_float2(__builtin_amdgcn_cosf(r), __builtin_amdgcn_sinf(r));
}

// Column pass: T[b,i,w] = sum_j s[b,i,j] * exp(i*2pi/128 * b_j * (w-64))
// grid 512 = (b, i-slab of 4), block 256; thread = (w = tid&127, g = tid>>7), 2 rows.
__global__ __launch_bounds__(256) void kB_colpass(
    const float* __restrict__ kin, const float* __restrict__ traj,
    float2* __restrict__ T)
{
    __shared__ float2 sS[4][RES];      // 4 KB  sampled rows
    __shared__ float2 FyT[32][RES];    // 32 KB twiddle tile (32 j-rows)
    __shared__ float  bjS[RES];        // 512 B column coords
    const int b   = blockIdx.x >> 5;
    const int i0  = (blockIdx.x & 31) * 4;
    const int tid = threadIdx.x;
    const int w   = tid & (RES - 1);
    const int g   = tid >> 7;                    // 0..1 -> rows i0+2g, i0+2g+1

    const float2* img = (const float2*)kin + b * NPTS;   // [H][W] complex
    const float2* tp  = (const float2*)traj;             // [M] (row, col)

    if (tid < RES) bjS[tid] = tp[tid].y;         // b_j for j = 0..127

    // ---- bilinear-sample 4 trajectory rows (512 pts, 2/thread)
    #pragma unroll
    for (int k = 0; k < 2; ++k) {
        int idx = tid + k * 256;                 // [0,512)
        int ii = idx >> 7;
        int j  = idx & (RES - 1);
        float2 t2 = tp[(i0 + ii) * RES + j];
        float pr = t2.x + 64.f, pc = t2.y + 64.f;
        float r0f = floorf(pr), c0f = floorf(pc);
        float wr = pr - r0f, wc = pc - c0f;
        int r0 = min(max((int)r0f, 0), RES - 1);
        int r1 = min(r0 + 1, RES - 1);
        int c0 = min(max((int)c0f, 0), RES - 1);
        int c1 = min(c0 + 1, RES - 1);
        float2 g00 = img[r0 * RES + c0], g01 = img[r0 * RES + c1];
        float2 g10 = img[r1 * RES + c0], g11 = img[r1 * RES + c1];
        float w00 = (1.f - wr) * (1.f - wc), w01 = (1.f - wr) * wc;
        float w10 = wr * (1.f - wc),         w11 = wr * wc;
        sS[ii][j] = make_float2(
            w00 * g00.x + w01 * g01.x + w10 * g10.x + w11 * g11.x,
            w00 * g00.y + w01 * g01.y + w10 * g10.y + w11 * g11.y);
    }

    float2 a0 = make_float2(0.f, 0.f), a1 = make_float2(0.f, 0.f);
    const float wf = (float)(w - 64) * 0.0078125f;       // (w-64)/128
    const int jh = 16 * g;                               // this thread's j-subrange

    for (int jt = 0; jt < 4; ++jt) {
        __syncthreads();                                 // FyT reuse (and sS on jt=0)
        // twiddle tile: FyT[jl][w] for jl in [jh, jh+16); lane-consecutive writes
        #pragma unroll
        for (int jj = 0; jj < 16; ++jj) {
            float bj = bjS[32 * jt + jh + jj];           // LDS broadcast
            FyT[jh + jj][w] = cis_rev(bj * wf);
        }
        __syncthreads();

        #pragma unroll 8
        for (int jj = 0; jj < 32; ++jj) {
            float2 fy = FyT[jj][w];                      // lane-consecutive b64
            float2 s0 = sS[2 * g + 0][32 * jt + jj];     // broadcast
            float2 s1 = sS[2 * g + 1][32 * jt + jj];     // broadcast
            cmac(a0, s0, fy);
            cmac(a1, s1, fy);
        }
    }

    T[(b * RES + i0 + 2 * g + 0) * RES + w] = a0;
    T[(b * RES + i0 + 2 * g + 1) * RES + w] = a1;
}

// Row pass: out[b,h,w] = sum_i exp(i*2pi/128 * a_i * (h-64)) * T[b,i,w]
// grid 512 = (b, h-slab of 4), block 256. Output planes [B,1,2,H,W].
__global__ __launch_bounds__(256) void kC_rowpass(
    const float2* __restrict__ T, const float* __restrict__ traj,
    float* __restrict__ out)
{
    __shared__ float2 fS[4][RES];      // 4 KB twiddles
    const int b   = blockIdx.x >> 5;
    const int h0  = (blockIdx.x & 31) * 4;
    const int tid = threadIdx.x;
    const int w   = tid & (RES - 1);
    const int g   = tid >> 7;                    // 0..1 -> rows h0+2g, h0+2g+1

    const float2* tp = (const float2*)traj;

    // twiddles: 512 entries, 2/thread; lane-consecutive writes, exact-rev hw sincos
    #pragma unroll
    for (int k = 0; k < 2; ++k) {
        int idx = tid + k * 256;                 // [0,512)
        int hh = idx >> 7;
        int i  = idx & (RES - 1);
        float ai = tp[i * RES].x;                // row coord of point (i, 0)
        fS[hh][i] = cis_rev(ai * (float)(h0 + hh - 64) * 0.0078125f);
    }
    __syncthreads();

    const float2* Tb = T + b * NPTS;
    float2 b0 = make_float2(0.f, 0.f), b1 = make_float2(0.f, 0.f);
    #pragma unroll 8
    for (int i = 0; i < RES; ++i) {
        float2 tv = Tb[i * RES + w];             // coalesced b64, L2-resident
        float2 f0 = fS[2 * g + 0][i];            // broadcast
        float2 f1 = fS[2 * g + 1][i];            // broadcast
        cmac(b0, f0, tv);
        cmac(b1, f1, tv);
    }

    float* o = out + b * 2 * NPTS;
    int h = h0 + 2 * g;
    o[h * RES + w]              = b0.x;
    o[NPTS + h * RES + w]       = b0.y;
    o[(h + 1) * RES + w]        = b1.x;
    o[NPTS + (h + 1) * RES + w] = b1.y;
}

extern "C" void kernel_launch(void* const* d_in, const int* in_sizes, int n_in,
                              void* d_out, int out_size, void* d_ws, size_t ws_size,
                              hipStream_t stream) {
    const float* kin  = (const float*)d_in[0];   // [16,1,128,128,2] f32
    const float* traj = (const float*)d_in[1];   // [16384,2] f32
    float* out = (float*)d_out;                  // [16,1,2,128,128] f32
    float2* T = (float2*)d_ws;                   // NB*NPTS float2

    kB_colpass<<<NB * (RES / 4), 256, 0, stream>>>(kin, traj, T);
    kC_rowpass<<<NB * (RES / 4), 256, 0, stream>>>(T, traj, out);
}

// Round 7
// 24.710 us; speedup vs baseline: 4.2867x; 1.0552x over previous
//
#include <hip/hip_runtime.h>

#define RES 128
#define NB 16
#define NPTS (RES * RES)

__device__ __forceinline__ void cmac(float2& a, float2 u, float2 v) {
    a.x = fmaf(u.x, v.x, fmaf(-u.y, v.y, a.x));
    a.y = fmaf(u.x, v.y, fmaf( u.y, v.x, a.y));
}

// exp(i*2*pi*rev) via hardware v_sin/v_cos (operand in revolutions, fract-reduced)
__device__ __forceinline__ float2 cis_rev(float rev) {
    float r = __builtin_amdgcn_fractf(rev);
    return make_float2(__builtin_amdgcn_cosf(r), __builtin_amdgcn_sinf(r));
}

// Column pass: T[b,i,w] = sum_j s[b,i,j] * exp(i*2pi/128 * b_j * (w-64))
// grid 256 = (b, 8-row i-slab), block 512; thread = (w = tid&127, g = tid>>7),
// accumulates rows i0+2g, i0+2g+1 (s-pair packed as float4 -> 1 LDS broadcast).
__global__ __launch_bounds__(512) void kB_colpass(
    const float* __restrict__ kin, const float* __restrict__ traj,
    float2* __restrict__ T)
{
    __shared__ float4 sSp[4][RES];        // 8 KB: sSp[p][j] = rows (2p, 2p+1) at j
    __shared__ float2 FyT[2][32][RES];    // 64 KB double-buffered twiddle tiles
    __shared__ float  bjS[RES];           // column coords b_j
    const int b   = blockIdx.x >> 4;
    const int i0  = (blockIdx.x & 15) * 8;
    const int tid = threadIdx.x;
    const int w   = tid & (RES - 1);
    const int g   = tid >> 7;                        // 0..3, wave-uniform

    const float2* img = (const float2*)kin + b * NPTS;   // [H][W] complex
    const float2* tp  = (const float2*)traj;             // [M] (row, col)

    if (tid < RES) bjS[tid] = tp[tid].y;

    // ---- bilinear-sample 8 trajectory rows (1024 pts, 2/thread)
    #pragma unroll
    for (int k = 0; k < 2; ++k) {
        int idx = tid + k * 512;                     // [0,1024)
        int ii = idx >> 7;                           // 0..7
        int j  = idx & (RES - 1);
        float2 t2 = tp[(i0 + ii) * RES + j];
        float pr = t2.x + 64.f, pc = t2.y + 64.f;
        float r0f = floorf(pr), c0f = floorf(pc);
        float wr = pr - r0f, wc = pc - c0f;
        int r0 = min(max((int)r0f, 0), RES - 1);
        int r1 = min(r0 + 1, RES - 1);
        int c0 = min(max((int)c0f, 0), RES - 1);
        int c1 = min(c0 + 1, RES - 1);
        float2 g00 = img[r0 * RES + c0], g01 = img[r0 * RES + c1];
        float2 g10 = img[r1 * RES + c0], g11 = img[r1 * RES + c1];
        float w00 = (1.f - wr) * (1.f - wc), w01 = (1.f - wr) * wc;
        float w10 = wr * (1.f - wc),         w11 = wr * wc;
        float2* dst = (float2*)&sSp[ii >> 1][j] + (ii & 1);
        *dst = make_float2(
            w00 * g00.x + w01 * g01.x + w10 * g10.x + w11 * g11.x,
            w00 * g00.y + w01 * g01.y + w10 * g10.y + w11 * g11.y);
    }
    __syncthreads();

    const float wf = (float)(w - 64) * 0.0078125f;   // (w-64)/128

    // gen tile t into buffer bf: rows [8g, 8g+8) of the 32-row tile, lane-consec writes
    auto gen = [&](int t, int bf) {
        #pragma unroll
        for (int q = 0; q < 8; ++q) {
            float bj = bjS[32 * t + 8 * g + q];      // broadcast
            FyT[bf][8 * g + q][w] = cis_rev(bj * wf);
        }
    };

    gen(0, 0);
    __syncthreads();

    float2 a0 = make_float2(0.f, 0.f), a1 = make_float2(0.f, 0.f);
    for (int t = 0; t < 4; ++t) {
        if (t < 3) gen(t + 1, (t + 1) & 1);
        #pragma unroll 8
        for (int jj = 0; jj < 32; ++jj) {
            float2 fy = FyT[t & 1][jj][w];           // lane-consecutive b64
            float4 sp = sSp[g][32 * t + jj];         // wave-uniform b128 broadcast
            cmac(a0, make_float2(sp.x, sp.y), fy);
            cmac(a1, make_float2(sp.z, sp.w), fy);
        }
        if (t < 3) __syncthreads();
    }

    T[(b * RES + i0 + 2 * g + 0) * RES + w] = a0;
    T[(b * RES + i0 + 2 * g + 1) * RES + w] = a1;
}

// Row pass: out[b,h,w] = sum_i exp(i*2pi/128 * a_i * (h-64)) * T[b,i,w]
// grid 256 = (b, 8-row h-slab), block 512; thread = (w, g) -> rows h0+2g, h0+2g+1.
__global__ __launch_bounds__(512) void kC_rowpass(
    const float2* __restrict__ T, const float* __restrict__ traj,
    float* __restrict__ out)
{
    __shared__ float4 fSp[4][RES];        // 8 KB: fSp[p][i] = rows (2p, 2p+1) at i
    const int b   = blockIdx.x >> 4;
    const int h0  = (blockIdx.x & 15) * 8;
    const int tid = threadIdx.x;
    const int w   = tid & (RES - 1);
    const int g   = tid >> 7;                        // 0..3, wave-uniform

    const float2* tp = (const float2*)traj;

    // twiddles: 1024 entries, 2/thread, hw sincos in revolutions
    #pragma unroll
    for (int k = 0; k < 2; ++k) {
        int idx = tid + k * 512;                     // [0,1024)
        int hh = idx >> 7;                           // 0..7
        int i  = idx & (RES - 1);
        float ai = tp[i * RES].x;                    // row coord of point (i, 0)
        float2* dst = (float2*)&fSp[hh >> 1][i] + (hh & 1);
        *dst = cis_rev(ai * (float)(h0 + hh - 64) * 0.0078125f);
    }
    __syncthreads();

    const float2* Tb = T + b * NPTS;
    float2 b0 = make_float2(0.f, 0.f), b1 = make_float2(0.f, 0.f);
    #pragma unroll 8
    for (int i = 0; i < RES; ++i) {
        float2 tv = Tb[i * RES + w];                 // coalesced b64, L2-resident
        float4 fp = fSp[g][i];                       // wave-uniform b128 broadcast
        cmac(b0, make_float2(fp.x, fp.y), tv);
        cmac(b1, make_float2(fp.z, fp.w), tv);
    }

    float* o = out + b * 2 * NPTS;
    int h = h0 + 2 * g;
    o[h * RES + w]              = b0.x;
    o[NPTS + h * RES + w]       = b0.y;
    o[(h + 1) * RES + w]        = b1.x;
    o[NPTS + (h + 1) * RES + w] = b1.y;
}

extern "C" void kernel_launch(void* const* d_in, const int* in_sizes, int n_in,
                              void* d_out, int out_size, void* d_ws, size_t ws_size,
                              hipStream_t stream) {
    const float* kin  = (const float*)d_in[0];   // [16,1,128,128,2] f32
    const float* traj = (const float*)d_in[1];   // [16384,2] f32
    float* out = (float*)d_out;                  // [16,1,2,128,128] f32
    float2* T = (float2*)d_ws;                   // NB*NPTS float2

    kB_colpass<<<NB * (RES / 8), 512, 0, stream>>>(kin, traj, T);
    kC_rowpass<<<NB * (RES / 8), 512, 0, stream>>>(T, traj, out);
}